// Round 7
// baseline (478.907 us; speedup 1.0000x reference)
//
#include <hip/hip_runtime.h>
#include <hip/hip_bf16.h>
#include <math.h>

#define N_EXPERTS 8
#define TOPK      2
#define IN_DIM    512
#define HID_DIM   1024
#define OUT_DIM   512
#define B_TOKENS  16384
#define NPAIRS    (B_TOKENS * TOPK)   // 32768 token-expert pairs (fixed!)
#define RB64      528                 // 64-row blocks covering padded rows (33792/64)
#define MAX_ROWS  (RB64 * 64)         // 33792

typedef __attribute__((ext_vector_type(8))) short short8;   // 8 bf16
typedef __attribute__((ext_vector_type(4))) float floatx4;

// ---- workspace layout (bytes) ----
#define WS_CNT     0          // 8 int
#define WS_CURSOR  32         // 8 int
#define WS_OFFS    64         // 9 int
#define WS_RBE     128        // 528 int (expert per 64-row block)
#define WS_TKIDX   2304       // 32768 int
#define WS_TKW     133376     // 32768 float
#define WS_ROWS    264448     // 33792 int
#define WS_WPOS    399616     // 33792 float
#define WS_W1T     534784     // 8*1024*512 bf16 = 8 MB
#define WS_W2T     8923392    // 8*512*1024 bf16 = 8 MB
#define WS_XBF     17312000   // 16384*512 bf16  = 16.8 MB
#define WS_H       34089216   // 33792*1024 bf16 = 69.2 MB (ends ~103.3 MB)

__device__ __forceinline__ short f2bf(float f) {
  unsigned u = __float_as_uint(f);
  unsigned r = (u + 0x7fffu + ((u >> 16) & 1u)) >> 16;  // RNE
  return (short)r;
}

// exact-GELU via Abramowitz-Stegun 7.1.26 erf (|eps|<=1.5e-7), ~13 VALU ops
// vs libm erff's ~25-30. Error negligible vs bf16 rounding of H.
__device__ __forceinline__ float fast_gelu(float h) {
  float z = fabsf(h) * 0.70710678118654752f;
  float t = __builtin_amdgcn_rcpf(fmaf(0.3275911f, z, 1.0f));
  float poly = fmaf(fmaf(fmaf(fmaf(1.061405429f, t, -1.453152027f),
                              t, 1.421413741f),
                         t, -0.284496736f),
                    t, 0.254829592f) * t;
  float erfv = 1.0f - poly * __expf(-z * z);
  erfv = copysignf(erfv, h);
  return 0.5f * h * (1.0f + erfv);
}

// ---------------- weight transpose + fp32->bf16 ----------------
// src [E][R][C] fp32 -> dst [E][C][R] bf16
__global__ __launch_bounds__(256) void transpose_cvt(const float* __restrict__ src,
                                                     short* __restrict__ dst,
                                                     int R, int C) {
  __shared__ float tile[32][33];
  int e = blockIdx.z;
  int r0 = blockIdx.y * 32, c0 = blockIdx.x * 32;
  const float* s = src + (size_t)e * R * C;
  short* d = dst + (size_t)e * R * C;
  int tr = threadIdx.x >> 5, tc = threadIdx.x & 31;
#pragma unroll
  for (int j = 0; j < 4; ++j)
    tile[tr + j * 8][tc] = s[(size_t)(r0 + tr + j * 8) * C + c0 + tc];
  __syncthreads();
#pragma unroll
  for (int j = 0; j < 4; ++j)
    d[(size_t)(c0 + tr + j * 8) * R + r0 + tc] = f2bf(tile[tc][tr + j * 8]);
}

// ---------------- gate: fp32 scores, top-2, softmax, counts; also emits xbf ----------------
__global__ __launch_bounds__(256) void gate_kernel(const float* __restrict__ x,
                                                   const float* __restrict__ gw,
                                                   const float* __restrict__ gb,
                                                   int* __restrict__ tkidx,
                                                   float* __restrict__ tkw,
                                                   int* __restrict__ cnt,
                                                   short* __restrict__ xbf) {
  __shared__ int lds_cnt[N_EXPERTS];
  if (threadIdx.x < N_EXPERTS) lds_cnt[threadIdx.x] = 0;
  __syncthreads();
  int w = threadIdx.x >> 6, lane = threadIdx.x & 63;
#pragma unroll 1
  for (int q = 0; q < 4; ++q) {
    int t = blockIdx.x * 16 + w * 4 + q;
    float s[8] = {0.f, 0.f, 0.f, 0.f, 0.f, 0.f, 0.f, 0.f};
#pragma unroll
    for (int it = 0; it < 8; ++it) {
      int i = it * 64 + lane;
      float xv = x[(size_t)t * IN_DIM + i];
      xbf[(size_t)t * IN_DIM + i] = f2bf(xv);      // fused fp32->bf16 emit
      const float4* gwr = (const float4*)(gw + (size_t)i * 8);
      float4 g0 = gwr[0], g1 = gwr[1];
      s[0] += xv * g0.x; s[1] += xv * g0.y; s[2] += xv * g0.z; s[3] += xv * g0.w;
      s[4] += xv * g1.x; s[5] += xv * g1.y; s[6] += xv * g1.z; s[7] += xv * g1.w;
    }
#pragma unroll
    for (int off = 32; off > 0; off >>= 1) {
#pragma unroll
      for (int j = 0; j < 8; ++j) s[j] += __shfl_xor(s[j], off);
    }
    if (lane == 0) {
      float v[8];
#pragma unroll
      for (int j = 0; j < 8; ++j) v[j] = s[j] + gb[j];
      int i1 = 0; float v1 = v[0];
#pragma unroll
      for (int j = 1; j < 8; ++j) if (v[j] > v1) { v1 = v[j]; i1 = j; }
      int i2 = -1; float v2 = -1e30f;
#pragma unroll
      for (int j = 0; j < 8; ++j) if (j != i1 && v[j] > v2) { v2 = v[j]; i2 = j; }
      float ex = expf(v2 - v1);
      float wa = 1.0f / (1.0f + ex);
      tkidx[t * 2] = i1; tkidx[t * 2 + 1] = i2;
      tkw[t * 2] = wa;  tkw[t * 2 + 1] = ex * wa;
      atomicAdd(&lds_cnt[i1], 1); atomicAdd(&lds_cnt[i2], 1);
    }
  }
  __syncthreads();
  if (threadIdx.x < N_EXPERTS) atomicAdd(&cnt[threadIdx.x], lds_cnt[threadIdx.x]);
}

// ---------------- offsets (padded to 128), rbe per 64-row block, pad zero, aux ----------------
__global__ __launch_bounds__(256) void offsets_kernel(const int* __restrict__ cnt,
                                                      int* __restrict__ offs,
                                                      int* __restrict__ rbe,
                                                      int* __restrict__ rows,
                                                      float* __restrict__ wpos,
                                                      float* __restrict__ aux_out) {
  __shared__ int off[N_EXPERTS + 1];
  if (threadIdx.x == 0) {
    int o = 0;
    float aux = 0.f;
    for (int e = 0; e < N_EXPERTS; ++e) {
      off[e] = o;
      o += (cnt[e] + 127) & ~127;
      float d = (float)cnt[e] / (float)NPAIRS - 1.0f / N_EXPERTS;
      aux += d * d;
    }
    off[N_EXPERTS] = o;
    aux_out[0] = aux / N_EXPERTS;
  }
  __syncthreads();
  if (threadIdx.x < N_EXPERTS + 1) offs[threadIdx.x] = off[threadIdx.x];
  for (int b = threadIdx.x; b < RB64; b += 256) {
    int r = b * 64, e = -1;
    for (int j = 0; j < N_EXPERTS; ++j)
      if (r >= off[j] && r < off[j + 1]) e = j;
    rbe[b] = e;
  }
  // zero pad entries so epilogues are branch-free (weight 0 -> adds 0)
  for (int idx = threadIdx.x; idx < N_EXPERTS * 128; idx += 256) {
    int e = idx >> 7, sl = idx & 127;
    int p = off[e] + cnt[e] + sl;
    if (p < off[e + 1]) { rows[p] = 0; wpos[p] = 0.f; }
  }
}

// ---------------- rank: block-aggregated position assignment (8 atomics/block) ----------------
__global__ __launch_bounds__(1024) void rank_kernel(const int* __restrict__ tkidx,
                                                    const float* __restrict__ tkw,
                                                    const int* __restrict__ offs,
                                                    int* __restrict__ cursor,
                                                    int* __restrict__ rows,
                                                    float* __restrict__ wpos) {
  __shared__ int wave_cnt[16][N_EXPERTS];
  __shared__ int wave_base[16][N_EXPERTS];
  __shared__ int blk_base[N_EXPERTS];
  const int tid = threadIdx.x, lane = tid & 63, w = tid >> 6;
  const int pr = blockIdx.x * 1024 + tid;
  const int e = tkidx[pr];
  int myrank = 0;
#pragma unroll
  for (int ei = 0; ei < N_EXPERTS; ++ei) {
    unsigned long long m = __ballot(e == ei);
    if (e == ei) myrank = __popcll(m & ((1ull << lane) - 1ull));
    if (lane == 0) wave_cnt[w][ei] = __popcll(m);
  }
  __syncthreads();
  if (tid < N_EXPERTS) {
    int base = 0;
#pragma unroll
    for (int ww = 0; ww < 16; ++ww) { wave_base[ww][tid] = base; base += wave_cnt[ww][tid]; }
    blk_base[tid] = atomicAdd(&cursor[tid], base);
  }
  __syncthreads();
  const int p = offs[e] + blk_base[e] + wave_base[w][e] + myrank;
  rows[p] = pr >> 1;
  wpos[p] = tkw[pr];
}

// ---------------- direct-streaming grouped GEMM: no LDS, no barriers ----------------
// Wave = 64x64 tile; A/B fragments loaded straight from global into VGPRs with
// 2-deep ping-pong prefetch; K advances via IMMEDIATE offsets (kk*64B <= 1984B)
// so the K-loop has zero address VALU. Compiler emits fine-grained vmcnt(N)
// (AITER-style MFMA<->load interleave). Block = 4 waves sharing the same 64
// rows (A lines hit L1 x4); same-rows blocks land on the same XCD.
// Each frag-load instr touches 16 full 64B lines (16 rows x 64B).
// MODE 0: H = gelu(A @ W1[e]^T + b1[e]) -> bf16   (KD=512,  ND=1024)
// MODE 1: atomicAdd(out[tok], w * (A @ W2[e]^T + b2[e]))  (KD=1024, ND=512)
template <int KD, int ND, int MODE, int GATHER>
__global__ __launch_bounds__(256, 3) void moe_gemm(const short* __restrict__ Asrc,
                                                   const short* __restrict__ Bmat,
                                                   const float* __restrict__ bias,
                                                   const int* __restrict__ rbe,
                                                   const int* __restrict__ rows,
                                                   const float* __restrict__ wpos,
                                                   short* __restrict__ Hout,
                                                   float* __restrict__ Oout) {
  constexpr int NBLK = ND / 256;
  const int bid = blockIdx.x;
  const int xcd = bid & 7, slab = bid >> 3;
  const int by = xcd * (RB64 / 8) + slab / NBLK;   // 66 row-blocks per XCD slab
  const int bx = slab % NBLK;
  const int e = rbe[by];
  if (e < 0) return;
  const int row0 = by * 64;
  const int tid = threadIdx.x, lane = tid & 63, w = tid >> 6;
  const int n0 = bx * 256 + w * 64;
  const int mlow = lane & 15, quad = lane >> 4;

  // per-lane base pointers (computed once; K-loop uses immediate offsets)
  const short* aB[4];
  const short* bB[4];
#pragma unroll
  for (int t = 0; t < 4; ++t) {
    int r = row0 + t * 16 + mlow;
    int sr = GATHER ? rows[r] : r;
    aB[t] = Asrc + (size_t)sr * KD + quad * 8;
    bB[t] = Bmat + (size_t)e * ND * KD + (size_t)(n0 + t * 16 + mlow) * KD + quad * 8;
  }

  floatx4 acc[4][4] = {};
  constexpr int KK = KD / 32;
  short8 af[2][4], bf[2][4];
#pragma unroll
  for (int s = 0; s < 2; ++s)
#pragma unroll
    for (int t = 0; t < 4; ++t) {
      af[s][t] = *(const short8*)(aB[t] + s * 32);
      bf[s][t] = *(const short8*)(bB[t] + s * 32);
    }
#pragma unroll
  for (int kk = 0; kk < KK; ++kk) {
    const int s = kk & 1;
#pragma unroll
    for (int t = 0; t < 4; ++t)
#pragma unroll
      for (int u = 0; u < 4; ++u)
        acc[t][u] = __builtin_amdgcn_mfma_f32_16x16x32_bf16(af[s][t], bf[s][u], acc[t][u], 0, 0, 0);
    if (kk + 2 < KK) {
#pragma unroll
      for (int t = 0; t < 4; ++t) {
        af[s][t] = *(const short8*)(aB[t] + (kk + 2) * 32);
        bf[s][t] = *(const short8*)(bB[t] + (kk + 2) * 32);
      }
    }
  }

  const float* be = bias + (size_t)e * ND;
  if (MODE == 0) {
#pragma unroll
    for (int t = 0; t < 4; ++t) {
      int gr = row0 + t * 16 + quad * 4;
#pragma unroll
      for (int u = 0; u < 4; ++u) {
        int gc = n0 + u * 16 + mlow;
        float bv = be[gc];
#pragma unroll
        for (int r = 0; r < 4; ++r) {
          float g = fast_gelu(acc[t][u][r] + bv);
          Hout[(size_t)(gr + r) * ND + gc] = f2bf(g);
        }
      }
    }
  } else {
#pragma unroll
    for (int t = 0; t < 4; ++t) {
      int pr = row0 + t * 16 + quad * 4;
#pragma unroll
      for (int r = 0; r < 4; ++r) {
        int p = pr + r;
        int tok = rows[p];
        float wt = wpos[p];
#pragma unroll
        for (int u = 0; u < 4; ++u) {
          int gc = n0 + u * 16 + mlow;
          float val = wt * (acc[t][u][r] + be[gc]);
          atomicAdd(Oout + (size_t)tok * OUT_DIM + gc, val);
        }
      }
    }
  }
}

extern "C" void kernel_launch(void* const* d_in, const int* in_sizes, int n_in,
                              void* d_out, int out_size, void* d_ws, size_t ws_size,
                              hipStream_t stream) {
  const float* x      = (const float*)d_in[0];
  const float* gate_w = (const float*)d_in[1];
  const float* gate_b = (const float*)d_in[2];
  const float* w1     = (const float*)d_in[3];
  const float* b1     = (const float*)d_in[4];
  const float* w2     = (const float*)d_in[5];
  const float* b2     = (const float*)d_in[6];
  float* out = (float*)d_out;
  char* ws = (char*)d_ws;

  int*   cnt    = (int*)(ws + WS_CNT);
  int*   cursor = (int*)(ws + WS_CURSOR);
  int*   offs   = (int*)(ws + WS_OFFS);
  int*   rbe    = (int*)(ws + WS_RBE);
  int*   tkidx  = (int*)(ws + WS_TKIDX);
  float* tkw    = (float*)(ws + WS_TKW);
  int*   rows   = (int*)(ws + WS_ROWS);
  float* wpos   = (float*)(ws + WS_WPOS);
  short* w1t    = (short*)(ws + WS_W1T);
  short* w2t    = (short*)(ws + WS_W2T);
  short* xbf    = (short*)(ws + WS_XBF);
  short* h      = (short*)(ws + WS_H);

  hipMemsetAsync(ws, 0, 128, stream);                                    // cnt+cursor+offs
  hipMemsetAsync(d_out, 0, (size_t)out_size * sizeof(float), stream);    // out accumulated by atomics

  transpose_cvt<<<dim3(HID_DIM / 32, IN_DIM / 32, N_EXPERTS), 256, 0, stream>>>(w1, w1t, IN_DIM, HID_DIM);
  transpose_cvt<<<dim3(OUT_DIM / 32, HID_DIM / 32, N_EXPERTS), 256, 0, stream>>>(w2, w2t, HID_DIM, OUT_DIM);

  gate_kernel<<<B_TOKENS / 16, 256, 0, stream>>>(x, gate_w, gate_b, tkidx, tkw, cnt, xbf);

  offsets_kernel<<<1, 256, 0, stream>>>(cnt, offs, rbe, rows, wpos, out + (size_t)B_TOKENS * OUT_DIM);

  rank_kernel<<<NPAIRS / 1024, 1024, 0, stream>>>(tkidx, tkw, offs, cursor, rows, wpos);

  moe_gemm<IN_DIM, HID_DIM, 0, 1><<<(HID_DIM / 256) * RB64, 256, 0, stream>>>(
      xbf, w1t, b1, rbe, rows, wpos, h, nullptr);

  moe_gemm<HID_DIM, OUT_DIM, 1, 0><<<(OUT_DIM / 256) * RB64, 256, 0, stream>>>(
      h, w2t, b2, rbe, rows, wpos, nullptr, out);
}